// Round 1
// baseline (490.106 us; speedup 1.0000x reference)
//
#include <hip/hip_runtime.h>
#include <math.h>

#define LSEQ 2048
#define DMODEL 768
#define NHEAD 12
#define DHEAD 64
#define NCHUNK 32   // 2048 / 64
#define CSIZE 64

// ---------------- LayerNorm ----------------
__global__ void ln_kernel(const float* __restrict__ x, const float* __restrict__ g,
                          const float* __restrict__ beta, float* __restrict__ xn) {
    int row = blockIdx.x;
    int tid = threadIdx.x;
    const float* xr = x + (size_t)row * DMODEL;
    float v0 = xr[tid], v1 = xr[tid + 256], v2 = xr[tid + 512];
    __shared__ float red[4];
    __shared__ float bc;
    float s = v0 + v1 + v2;
#pragma unroll
    for (int o = 32; o > 0; o >>= 1) s += __shfl_down(s, o);
    if ((tid & 63) == 0) red[tid >> 6] = s;
    __syncthreads();
    if (tid == 0) bc = (red[0] + red[1] + red[2] + red[3]) * (1.0f / DMODEL);
    __syncthreads();
    float mu = bc;
    float d0 = v0 - mu, d1 = v1 - mu, d2 = v2 - mu;
    float vs = d0 * d0 + d1 * d1 + d2 * d2;
    __syncthreads();
#pragma unroll
    for (int o = 32; o > 0; o >>= 1) vs += __shfl_down(vs, o);
    if ((tid & 63) == 0) red[tid >> 6] = vs;
    __syncthreads();
    if (tid == 0) bc = rsqrtf((red[0] + red[1] + red[2] + red[3]) * (1.0f / DMODEL) + 1e-5f);
    __syncthreads();
    float r = bc;
    float* xo = xn + (size_t)row * DMODEL;
    xo[tid]       = d0 * r * g[tid]       + beta[tid];
    xo[tid + 256] = d1 * r * g[tid + 256] + beta[tid + 256];
    xo[tid + 512] = d2 * r * g[tid + 512] + beta[tid + 512];
}

// ---------------- Generic fp32 GEMM: C[M,N] = A[M,K]@B[K,N] + bias ----------------
// grid = (N/64, M/64), block = 256, each thread 4x4.
__global__ void gemm_bias_kernel(const float* __restrict__ A, const float* __restrict__ B,
                                 const float* __restrict__ bias, float* __restrict__ C,
                                 int N, int K) {
    __shared__ float As[16][64];
    __shared__ float Bs[16][64];
    int tid = threadIdx.x;
    int tx = tid & 15, ty = tid >> 4;
    int ar = tid >> 2;           // row within A tile
    int ak = (tid & 3) * 4;      // k within A tile
    int bk = tid >> 4;           // k within B tile
    int bc = (tid & 15) * 4;     // col within B tile
    float acc[4][4] = {};
    const float* Aptr = A + (size_t)(blockIdx.y * 64 + ar) * K + ak;
    const float* Bptr = B + (size_t)bk * N + blockIdx.x * 64 + bc;
    for (int k0 = 0; k0 < K; k0 += 16) {
        float4 av = *(const float4*)(Aptr + k0);
        float4 bv = *(const float4*)(Bptr + (size_t)k0 * N);
        As[ak + 0][ar] = av.x; As[ak + 1][ar] = av.y;
        As[ak + 2][ar] = av.z; As[ak + 3][ar] = av.w;
        *(float4*)&Bs[bk][bc] = bv;
        __syncthreads();
#pragma unroll
        for (int kk = 0; kk < 16; kk++) {
            float4 a = *(const float4*)&As[kk][ty * 4];
            float4 b = *(const float4*)&Bs[kk][tx * 4];
            acc[0][0] += a.x * b.x; acc[0][1] += a.x * b.y; acc[0][2] += a.x * b.z; acc[0][3] += a.x * b.w;
            acc[1][0] += a.y * b.x; acc[1][1] += a.y * b.y; acc[1][2] += a.y * b.z; acc[1][3] += a.y * b.w;
            acc[2][0] += a.z * b.x; acc[2][1] += a.z * b.y; acc[2][2] += a.z * b.z; acc[2][3] += a.z * b.w;
            acc[3][0] += a.w * b.x; acc[3][1] += a.w * b.y; acc[3][2] += a.w * b.z; acc[3][3] += a.w * b.w;
        }
        __syncthreads();
    }
    float4 bv = *(const float4*)&bias[blockIdx.x * 64 + tx * 4];
#pragma unroll
    for (int i = 0; i < 4; i++) {
        float4 o;
        o.x = acc[i][0] + bv.x; o.y = acc[i][1] + bv.y;
        o.z = acc[i][2] + bv.z; o.w = acc[i][3] + bv.w;
        *(float4*)&C[(size_t)(blockIdx.y * 64 + ty * 4 + i) * N + blockIdx.x * 64 + tx * 4] = o;
    }
}

// ---------------- gate + feature map (elementwise over L*D) ----------------
__device__ __forceinline__ float softplus_f(float x) {
    return (x > 15.f) ? x : log1pf(expf(x));
}

__global__ void gate_feat_kernel(const float* __restrict__ qkv, const float* __restrict__ sem,
                                 const float* __restrict__ ctx, float* __restrict__ qf,
                                 float* __restrict__ kf) {
    int idx = blockIdx.x * 256 + threadIdx.x;   // < L*D exactly
    int l = idx / DMODEL, d = idx - l * DMODEL;
    size_t sbase = (size_t)l * (2 * DMODEL);
    float sa = sem[sbase + d], sp = sem[sbase + DMODEL + d];
    float ca = ctx[sbase + d], cp = ctx[sbase + DMODEL + d];
    float amp = softplus_f(sa) * softplus_f(ca);
    float t = amp * cosf(sp - cp);
    float gate = 1.0f / (1.0f + expf(-t));
    size_t qbase = (size_t)l * (3 * DMODEL);
    float q = qkv[qbase + d];
    float k = qkv[qbase + DMODEL + d] * gate;
    qf[idx] = (q > 0.f) ? q + 1.0f : expf(q);   // elu(q)+1
    kf[idx] = (k > 0.f) ? k + 1.0f : expf(k);   // elu(k)+1
}

// ---------------- per-(head,chunk) KV state sums ----------------
__global__ void chunk_sum_kernel(const float* __restrict__ kf, const float* __restrict__ qkv,
                                 float* __restrict__ S) {
    int h = blockIdx.x % NHEAD;
    int c = blockIdx.x / NHEAD;
    __shared__ float ks[64][64];
    __shared__ float vs[64][64];
    int tid = threadIdx.x;
#pragma unroll
    for (int it = 0; it < 4; it++) {
        int r = it * 16 + (tid >> 4);
        int cc = (tid & 15) * 4;
        int lg = c * 64 + r;
        *(float4*)&ks[r][cc] = *(const float4*)&kf[(size_t)lg * DMODEL + h * DHEAD + cc];
        *(float4*)&vs[r][cc] = *(const float4*)&qkv[(size_t)lg * (3 * DMODEL) + 2 * DMODEL + h * DHEAD + cc];
    }
    __syncthreads();
    int d = tid >> 2;
    int e0 = (tid & 3) * 16;
    float acc[16] = {};
    float ksum = 0.f;
    for (int l = 0; l < 64; l++) {
        float kd = ks[l][d];
        ksum += kd;
#pragma unroll
        for (int u = 0; u < 16; u++) acc[u] += kd * vs[l][e0 + u];
    }
    float* Sp = S + ((size_t)(h * NCHUNK + c)) * 4160;
#pragma unroll
    for (int u = 0; u < 16; u++) Sp[d * 64 + e0 + u] = acc[u];
    if ((tid & 3) == 0) Sp[4096 + d] = ksum;
}

// ---------------- exclusive prefix over chunks ----------------
__global__ void prefix_kernel(const float* __restrict__ S, float* __restrict__ P) {
    int h = blockIdx.x;
    int i = blockIdx.y * 256 + threadIdx.x;
    if (i >= 4160) return;
    float run = 0.f;
    for (int c = 0; c < NCHUNK; c++) {
        size_t off = ((size_t)(h * NCHUNK + c)) * 4160 + i;
        float v = S[off];
        P[off] = run;
        run += v;
    }
}

// ---------------- per-(head,chunk) output ----------------
__global__ void attn_out_kernel(const float* __restrict__ qf, const float* __restrict__ kfb,
                                const float* __restrict__ qkv, const float* __restrict__ P,
                                float* __restrict__ attn) {
    int h = blockIdx.x % NHEAD;
    int c = blockIdx.x / NHEAD;
    __shared__ float qs[64][64];
    __shared__ float b1[64][64];   // stage1: P tile; stage2: K tile
    __shared__ float b2[64][64];   // stage1: kp (row 0); stage2: V tile
    int tid = threadIdx.x;
    const size_t pbase = ((size_t)(h * NCHUNK + c)) * 4160;
#pragma unroll
    for (int it = 0; it < 4; it++) {
        int r = it * 16 + (tid >> 4);
        int cc = (tid & 15) * 4;
        int lg = c * 64 + r;
        *(float4*)&qs[r][cc] = *(const float4*)&qf[(size_t)lg * DMODEL + h * DHEAD + cc];
        *(float4*)&b1[r][cc] = *(const float4*)&P[pbase + r * 64 + cc];
    }
    if (tid < 16) *(float4*)&b2[0][tid * 4] = *(const float4*)&P[pbase + 4096 + tid * 4];
    __syncthreads();
    int l = tid >> 2;
    int e0 = (tid & 3) * 16;
    float qreg[64];
#pragma unroll
    for (int d = 0; d < 64; d++) qreg[d] = qs[l][d];
    float num[16] = {};
    float den = 1e-6f;   // DEN_EPS
    for (int d = 0; d < 64; d++) {
        float qd = qreg[d];
        den += qd * b2[0][d];
#pragma unroll
        for (int u = 0; u < 16; u++) num[u] += qd * b1[d][e0 + u];
    }
    __syncthreads();
#pragma unroll
    for (int it = 0; it < 4; it++) {
        int r = it * 16 + (tid >> 4);
        int cc = (tid & 15) * 4;
        int lg = c * 64 + r;
        *(float4*)&b1[r][cc] = *(const float4*)&kfb[(size_t)lg * DMODEL + h * DHEAD + cc];
        *(float4*)&b2[r][cc] = *(const float4*)&qkv[(size_t)lg * (3 * DMODEL) + 2 * DMODEL + h * DHEAD + cc];
    }
    __syncthreads();
    for (int j = 0; j <= l; j++) {
        float a = 0.f;
#pragma unroll
        for (int d = 0; d < 64; d++) a += qreg[d] * b1[j][d];
        den += a;
#pragma unroll
        for (int u = 0; u < 16; u++) num[u] += a * b2[j][e0 + u];
    }
    float inv = 1.0f / den;
    float* op = attn + (size_t)(c * 64 + l) * DMODEL + h * DHEAD + e0;
#pragma unroll
    for (int u = 0; u < 16; u++) op[u] = num[u] * inv;
}

extern "C" void kernel_launch(void* const* d_in, const int* in_sizes, int n_in,
                              void* d_out, int out_size, void* d_ws, size_t ws_size,
                              hipStream_t stream) {
    const float* x      = (const float*)d_in[0];
    const float* W_qkv  = (const float*)d_in[1];
    const float* b_qkv  = (const float*)d_in[2];
    const float* W_sem  = (const float*)d_in[3];
    const float* b_sem  = (const float*)d_in[4];
    const float* W_ctx  = (const float*)d_in[5];
    const float* b_ctx  = (const float*)d_in[6];
    const float* W_proj = (const float*)d_in[7];
    const float* b_proj = (const float*)d_in[8];
    const float* ln_g   = (const float*)d_in[9];
    const float* ln_b   = (const float*)d_in[10];
    float* out = (float*)d_out;
    float* ws  = (float*)d_ws;

    // workspace layout (floats); total 15728640 floats = 62.9 MB
    float* xn   = ws;                  // 1572864 (reused as attn later)
    float* qkv  = ws + 1572864;        // 4718592
    float* sem  = ws + 6291456;        // 3145728
    float* ctx  = ws + 9437184;        // 3145728
    float* qf   = ws + 12582912;       // 1572864
    float* kf   = ws + 14155776;       // 1572864
    float* S    = sem;                 // reuse: sem dead after gate_feat
    float* Px   = sem + 1597440;       // reuse: spills into ctx region (also dead)
    float* attn = xn;                  // reuse: xn dead after qkv GEMM

    ln_kernel<<<LSEQ, 256, 0, stream>>>(x, ln_g, ln_b, xn);
    gemm_bias_kernel<<<dim3(2304 / 64, LSEQ / 64), 256, 0, stream>>>(xn, W_qkv, b_qkv, qkv, 2304, 768);
    gemm_bias_kernel<<<dim3(1536 / 64, LSEQ / 64), 256, 0, stream>>>(x, W_sem, b_sem, sem, 1536, 768);
    gemm_bias_kernel<<<dim3(1536 / 64, LSEQ / 64), 256, 0, stream>>>(x, W_ctx, b_ctx, ctx, 1536, 768);
    gate_feat_kernel<<<(LSEQ * DMODEL) / 256, 256, 0, stream>>>(qkv, sem, ctx, qf, kf);
    chunk_sum_kernel<<<NHEAD * NCHUNK, 256, 0, stream>>>(kf, qkv, S);
    prefix_kernel<<<dim3(NHEAD, 17), 256, 0, stream>>>(S, Px);
    attn_out_kernel<<<NHEAD * NCHUNK, 256, 0, stream>>>(qf, kf, qkv, Px, attn);
    gemm_bias_kernel<<<dim3(768 / 64, LSEQ / 64), 256, 0, stream>>>(attn, W_proj, b_proj, out, 768, 768);
}

// Round 2
// 252.505 us; speedup vs baseline: 1.9410x; 1.9410x over previous
//
#include <hip/hip_runtime.h>
#include <math.h>

#define LSEQ 2048
#define DMODEL 768
#define NHEAD 12
#define DHEAD 64
#define NCHUNK 32   // 2048 / 64
#define CSIZE 64

typedef unsigned short ushort_t;
typedef __attribute__((ext_vector_type(8))) short short8;
typedef float float4v __attribute__((ext_vector_type(4)));

__device__ __forceinline__ ushort_t f2b(float f) {
    union { float f; unsigned int u; } v; v.f = f;
    unsigned int u = v.u;
    return (ushort_t)((u + 0x7fffu + ((u >> 16) & 1u)) >> 16);
}

// ---------------- cast fp32 -> bf16 (8 elems/thread) ----------------
__global__ void f2b_kernel(const float* __restrict__ src, ushort_t* __restrict__ dst) {
    int i = (blockIdx.x * 256 + threadIdx.x) * 8;
    float4 a = *(const float4*)&src[i];
    float4 b = *(const float4*)&src[i + 4];
    ushort_t ob[8];
    ob[0] = f2b(a.x); ob[1] = f2b(a.y); ob[2] = f2b(a.z); ob[3] = f2b(a.w);
    ob[4] = f2b(b.x); ob[5] = f2b(b.y); ob[6] = f2b(b.z); ob[7] = f2b(b.w);
    *(uint4*)&dst[i] = *(uint4*)ob;
}

// ---------------- transpose + convert weight: W[K][N] f32 -> Wt[N][K] bf16 ----------------
__global__ void transpose_b_kernel(const float* __restrict__ W, ushort_t* __restrict__ Wt,
                                   int K, int N) {
    __shared__ float tile[32][33];
    int tid = threadIdx.x;
    int tr = tid >> 5, tc = tid & 31;
    int kbase = blockIdx.y * 32, nbase = blockIdx.x * 32;
#pragma unroll
    for (int p = 0; p < 4; p++) {
        int r = p * 8 + tr;
        tile[r][tc] = W[(size_t)(kbase + r) * N + nbase + tc];
    }
    __syncthreads();
#pragma unroll
    for (int p = 0; p < 4; p++) {
        int r = p * 8 + tr;
        Wt[(size_t)(nbase + r) * K + kbase + tc] = f2b(tile[tc][r]);
    }
}

// ---------------- LayerNorm (bf16 output) ----------------
__global__ void ln_kernel(const float* __restrict__ x, const float* __restrict__ g,
                          const float* __restrict__ beta, ushort_t* __restrict__ xn) {
    int row = blockIdx.x;
    int tid = threadIdx.x;
    const float* xr = x + (size_t)row * DMODEL;
    float v0 = xr[tid], v1 = xr[tid + 256], v2 = xr[tid + 512];
    __shared__ float red[4];
    __shared__ float bc;
    float s = v0 + v1 + v2;
#pragma unroll
    for (int o = 32; o > 0; o >>= 1) s += __shfl_down(s, o);
    if ((tid & 63) == 0) red[tid >> 6] = s;
    __syncthreads();
    if (tid == 0) bc = (red[0] + red[1] + red[2] + red[3]) * (1.0f / DMODEL);
    __syncthreads();
    float mu = bc;
    float d0 = v0 - mu, d1 = v1 - mu, d2 = v2 - mu;
    float vs = d0 * d0 + d1 * d1 + d2 * d2;
    __syncthreads();
#pragma unroll
    for (int o = 32; o > 0; o >>= 1) vs += __shfl_down(vs, o);
    if ((tid & 63) == 0) red[tid >> 6] = vs;
    __syncthreads();
    if (tid == 0) bc = rsqrtf((red[0] + red[1] + red[2] + red[3]) * (1.0f / DMODEL) + 1e-5f);
    __syncthreads();
    float r = bc;
    ushort_t* xo = xn + (size_t)row * DMODEL;
    xo[tid]       = f2b(d0 * r * g[tid]       + beta[tid]);
    xo[tid + 256] = f2b(d1 * r * g[tid + 256] + beta[tid + 256]);
    xo[tid + 512] = f2b(d2 * r * g[tid + 512] + beta[tid + 512]);
}

// ---------------- bf16 MFMA GEMM: C[M,N] = A[M,K] @ Bt[N,K]^T + bias ----------------
// 128x128 tile, BK=32, 256 threads (4 waves, 2x2), each wave 4x4 16x16x32 MFMAs.
__global__ __launch_bounds__(256) void gemm_mfma_kernel(
    const ushort_t* __restrict__ A, const ushort_t* __restrict__ Bt,
    const float* __restrict__ bias, float* __restrict__ C,
    int N, int K) {
    __shared__ ushort_t As[128 * 32];
    __shared__ ushort_t Bs[128 * 32];
    int tid = threadIdx.x;
    int wave = tid >> 6, lane = tid & 63;
    int wm = (wave >> 1) * 64, wn = (wave & 1) * 64;
    int quad = lane >> 4, l16 = lane & 15;
    int m0 = blockIdx.y * 128, n0 = blockIdx.x * 128;

    float4v acc[4][4];
#pragma unroll
    for (int i = 0; i < 4; i++)
#pragma unroll
        for (int j = 0; j < 4; j++)
#pragma unroll
            for (int r = 0; r < 4; r++) acc[i][j][r] = 0.0f;

    for (int k0 = 0; k0 < K; k0 += 32) {
        // stage A and B tiles: 128 rows x 32 k each; 512 16B-chunks per tile
#pragma unroll
        for (int p = 0; p < 2; p++) {
            int chunk = p * 256 + tid;
            int r = chunk >> 2;
            int kc = (chunk & 3) * 8;
            *(uint4*)&As[r * 32 + kc] = *(const uint4*)&A[(size_t)(m0 + r) * K + k0 + kc];
            *(uint4*)&Bs[r * 32 + kc] = *(const uint4*)&Bt[(size_t)(n0 + r) * K + k0 + kc];
        }
        __syncthreads();
        short8 af[4], bf[4];
#pragma unroll
        for (int i = 0; i < 4; i++) af[i] = *(const short8*)&As[(wm + i * 16 + l16) * 32 + quad * 8];
#pragma unroll
        for (int j = 0; j < 4; j++) bf[j] = *(const short8*)&Bs[(wn + j * 16 + l16) * 32 + quad * 8];
#pragma unroll
        for (int i = 0; i < 4; i++)
#pragma unroll
            for (int j = 0; j < 4; j++)
                acc[i][j] = __builtin_amdgcn_mfma_f32_16x16x32_bf16(af[i], bf[j], acc[i][j], 0, 0, 0);
        __syncthreads();
    }
#pragma unroll
    for (int i = 0; i < 4; i++) {
#pragma unroll
        for (int j = 0; j < 4; j++) {
            int col = n0 + wn + j * 16 + l16;
            float bv = bias[col];
#pragma unroll
            for (int r = 0; r < 4; r++) {
                int row = m0 + wm + i * 16 + quad * 4 + r;
                C[(size_t)row * N + col] = acc[i][j][r] + bv;
            }
        }
    }
}

// ---------------- gate + feature map (elementwise over L*D) ----------------
__device__ __forceinline__ float softplus_f(float x) {
    return (x > 15.f) ? x : log1pf(expf(x));
}

__global__ void gate_feat_kernel(const float* __restrict__ qkv, const float* __restrict__ sem,
                                 const float* __restrict__ ctx, float* __restrict__ qf,
                                 float* __restrict__ kf) {
    int idx = blockIdx.x * 256 + threadIdx.x;   // < L*D exactly
    int l = idx / DMODEL, d = idx - l * DMODEL;
    size_t sbase = (size_t)l * (2 * DMODEL);
    float sa = sem[sbase + d], sp = sem[sbase + DMODEL + d];
    float ca = ctx[sbase + d], cp = ctx[sbase + DMODEL + d];
    float amp = softplus_f(sa) * softplus_f(ca);
    float t = amp * cosf(sp - cp);
    float gate = 1.0f / (1.0f + expf(-t));
    size_t qbase = (size_t)l * (3 * DMODEL);
    float q = qkv[qbase + d];
    float k = qkv[qbase + DMODEL + d] * gate;
    qf[idx] = (q > 0.f) ? q + 1.0f : expf(q);   // elu(q)+1
    kf[idx] = (k > 0.f) ? k + 1.0f : expf(k);   // elu(k)+1
}

// ---------------- per-(head,chunk) KV state sums ----------------
__global__ void chunk_sum_kernel(const float* __restrict__ kf, const float* __restrict__ qkv,
                                 float* __restrict__ S) {
    int h = blockIdx.x % NHEAD;
    int c = blockIdx.x / NHEAD;
    __shared__ float ks[64][64];
    __shared__ float vs[64][64];
    int tid = threadIdx.x;
#pragma unroll
    for (int it = 0; it < 4; it++) {
        int r = it * 16 + (tid >> 4);
        int cc = (tid & 15) * 4;
        int lg = c * 64 + r;
        *(float4*)&ks[r][cc] = *(const float4*)&kf[(size_t)lg * DMODEL + h * DHEAD + cc];
        *(float4*)&vs[r][cc] = *(const float4*)&qkv[(size_t)lg * (3 * DMODEL) + 2 * DMODEL + h * DHEAD + cc];
    }
    __syncthreads();
    int d = tid >> 2;
    int e0 = (tid & 3) * 16;
    float acc[16] = {};
    float ksum = 0.f;
    for (int l = 0; l < 64; l++) {
        float kd = ks[l][d];
        ksum += kd;
#pragma unroll
        for (int u = 0; u < 16; u++) acc[u] += kd * vs[l][e0 + u];
    }
    float* Sp = S + ((size_t)(h * NCHUNK + c)) * 4160;
#pragma unroll
    for (int u = 0; u < 16; u++) Sp[d * 64 + e0 + u] = acc[u];
    if ((tid & 3) == 0) Sp[4096 + d] = ksum;
}

// ---------------- exclusive prefix over chunks ----------------
__global__ void prefix_kernel(const float* __restrict__ S, float* __restrict__ P) {
    int h = blockIdx.x;
    int i = blockIdx.y * 256 + threadIdx.x;
    if (i >= 4160) return;
    float run = 0.f;
    for (int c = 0; c < NCHUNK; c++) {
        size_t off = ((size_t)(h * NCHUNK + c)) * 4160 + i;
        float v = S[off];
        P[off] = run;
        run += v;
    }
}

// ---------------- per-(head,chunk) output (bf16 attn out) ----------------
__global__ void attn_out_kernel(const float* __restrict__ qf, const float* __restrict__ kfb,
                                const float* __restrict__ qkv, const float* __restrict__ P,
                                ushort_t* __restrict__ attn) {
    int h = blockIdx.x % NHEAD;
    int c = blockIdx.x / NHEAD;
    __shared__ float qs[64][64];
    __shared__ float b1[64][64];   // stage1: P tile; stage2: K tile
    __shared__ float b2[64][64];   // stage1: kp (row 0); stage2: V tile
    int tid = threadIdx.x;
    const size_t pbase = ((size_t)(h * NCHUNK + c)) * 4160;
#pragma unroll
    for (int it = 0; it < 4; it++) {
        int r = it * 16 + (tid >> 4);
        int cc = (tid & 15) * 4;
        int lg = c * 64 + r;
        *(float4*)&qs[r][cc] = *(const float4*)&qf[(size_t)lg * DMODEL + h * DHEAD + cc];
        *(float4*)&b1[r][cc] = *(const float4*)&P[pbase + r * 64 + cc];
    }
    if (tid < 16) *(float4*)&b2[0][tid * 4] = *(const float4*)&P[pbase + 4096 + tid * 4];
    __syncthreads();
    int l = tid >> 2;
    int e0 = (tid & 3) * 16;
    float qreg[64];
#pragma unroll
    for (int d = 0; d < 64; d++) qreg[d] = qs[l][d];
    float num[16] = {};
    float den = 1e-6f;   // DEN_EPS
    for (int d = 0; d < 64; d++) {
        float qd = qreg[d];
        den += qd * b2[0][d];
#pragma unroll
        for (int u = 0; u < 16; u++) num[u] += qd * b1[d][e0 + u];
    }
    __syncthreads();
#pragma unroll
    for (int it = 0; it < 4; it++) {
        int r = it * 16 + (tid >> 4);
        int cc = (tid & 15) * 4;
        int lg = c * 64 + r;
        *(float4*)&b1[r][cc] = *(const float4*)&kfb[(size_t)lg * DMODEL + h * DHEAD + cc];
        *(float4*)&b2[r][cc] = *(const float4*)&qkv[(size_t)lg * (3 * DMODEL) + 2 * DMODEL + h * DHEAD + cc];
    }
    __syncthreads();
    for (int j = 0; j <= l; j++) {
        float a = 0.f;
#pragma unroll
        for (int d = 0; d < 64; d++) a += qreg[d] * b1[j][d];
        den += a;
#pragma unroll
        for (int u = 0; u < 16; u++) num[u] += a * b2[j][e0 + u];
    }
    float inv = 1.0f / den;
    ushort_t ob[16];
#pragma unroll
    for (int u = 0; u < 16; u++) ob[u] = f2b(num[u] * inv);
    ushort_t* op = attn + (size_t)(c * 64 + l) * DMODEL + h * DHEAD + e0;
    *(uint4*)&op[0] = *(uint4*)&ob[0];
    *(uint4*)&op[8] = *(uint4*)&ob[8];
}

extern "C" void kernel_launch(void* const* d_in, const int* in_sizes, int n_in,
                              void* d_out, int out_size, void* d_ws, size_t ws_size,
                              hipStream_t stream) {
    const float* x      = (const float*)d_in[0];
    const float* W_qkv  = (const float*)d_in[1];
    const float* b_qkv  = (const float*)d_in[2];
    const float* W_sem  = (const float*)d_in[3];
    const float* b_sem  = (const float*)d_in[4];
    const float* W_ctx  = (const float*)d_in[5];
    const float* b_ctx  = (const float*)d_in[6];
    const float* W_proj = (const float*)d_in[7];
    const float* b_proj = (const float*)d_in[8];
    const float* ln_g   = (const float*)d_in[9];
    const float* ln_b   = (const float*)d_in[10];
    float* out = (float*)d_out;
    float* ws  = (float*)d_ws;

    // ---- workspace layout (float offsets), total 15,728,640 floats = 62.9 MB ----
    // R region [0 .. 1,572,864): Wt_qkv (884,736 f) + Wt_proj (294,912 f)
    ushort_t* Wt_qkv  = (ushort_t*)(ws);                       // 2304*768 us
    ushort_t* Wt_proj = (ushort_t*)(ws + 884736);              // 768*768 us
    float* qkv = ws + 1572864;                                 // 2048*2304
    float* sem = ws + 6291456;                                 // 2048*1536
    float* ctx = ws + 9437184;                                 // 2048*1536
    float* qf  = ws + 12582912;                                // 2048*768
    float* kf  = ws + 14155776;                                // 2048*768
    // overlays:
    ushort_t* xb     = (ushort_t*)qf;                          // dead before gate_feat writes qf
    ushort_t* Wt_sem = (ushort_t*)(qf + 786432);               // 1536*768 us, dead before gate_feat
    ushort_t* xnb    = (ushort_t*)kf;                          // dead after qkv GEMM
    ushort_t* Wt_ctx = (ushort_t*)(kf + 786432);               // dead before gate_feat
    float* S  = sem;                                           // 12*32*4160, after sem dead
    float* Px = ctx;                                           // after ctx dead
    ushort_t* attnb = (ushort_t*)sem;                          // S dead during attn_out

    // casts + transposes
    f2b_kernel<<<(LSEQ * DMODEL) / (256 * 8), 256, 0, stream>>>(x, xb);
    ln_kernel<<<LSEQ, 256, 0, stream>>>(x, ln_g, ln_b, xnb);
    transpose_b_kernel<<<dim3(2304 / 32, 768 / 32), 256, 0, stream>>>(W_qkv, Wt_qkv, 768, 2304);
    transpose_b_kernel<<<dim3(1536 / 32, 768 / 32), 256, 0, stream>>>(W_sem, Wt_sem, 768, 1536);
    transpose_b_kernel<<<dim3(1536 / 32, 768 / 32), 256, 0, stream>>>(W_ctx, Wt_ctx, 768, 1536);
    transpose_b_kernel<<<dim3(768 / 32, 768 / 32), 256, 0, stream>>>(W_proj, Wt_proj, 768, 768);

    // GEMMs (bf16 MFMA)
    gemm_mfma_kernel<<<dim3(2304 / 128, LSEQ / 128), 256, 0, stream>>>(xnb, Wt_qkv, b_qkv, qkv, 2304, 768);
    gemm_mfma_kernel<<<dim3(1536 / 128, LSEQ / 128), 256, 0, stream>>>(xb, Wt_sem, b_sem, sem, 1536, 768);
    gemm_mfma_kernel<<<dim3(1536 / 128, LSEQ / 128), 256, 0, stream>>>(xb, Wt_ctx, b_ctx, ctx, 1536, 768);

    // attention path
    gate_feat_kernel<<<(LSEQ * DMODEL) / 256, 256, 0, stream>>>(qkv, sem, ctx, qf, kf);
    chunk_sum_kernel<<<NHEAD * NCHUNK, 256, 0, stream>>>(kf, qkv, S);
    prefix_kernel<<<dim3(NHEAD, 17), 256, 0, stream>>>(S, Px);
    attn_out_kernel<<<NHEAD * NCHUNK, 256, 0, stream>>>(qf, kf, qkv, Px, attnb);

    // output projection
    gemm_mfma_kernel<<<dim3(768 / 128, LSEQ / 128), 256, 0, stream>>>(attnb, Wt_proj, b_proj, out, 768, 768);
}

// Round 3
// 227.956 us; speedup vs baseline: 2.1500x; 1.1077x over previous
//
#include <hip/hip_runtime.h>
#include <math.h>

#define LSEQ 2048
#define DMODEL 768
#define NHEAD 12
#define DHEAD 64
#define NCHUNK 32   // 2048 / 64
#define CSIZE 64

typedef unsigned short ushort_t;
typedef __attribute__((ext_vector_type(8))) short short8;
typedef float float4v __attribute__((ext_vector_type(4)));

__device__ __forceinline__ ushort_t f2b(float f) {
    union { float f; unsigned int u; } v; v.f = f;
    unsigned int u = v.u;
    return (ushort_t)((u + 0x7fffu + ((u >> 16) & 1u)) >> 16);
}

// async 16B global->LDS (wave-uniform LDS base + lane*16)
__device__ __forceinline__ void gl_lds16(const ushort_t* g, ushort_t* l) {
    __builtin_amdgcn_global_load_lds(
        (const __attribute__((address_space(1))) unsigned int*)g,
        (__attribute__((address_space(3))) unsigned int*)l, 16, 0, 0);
}

// ---------------- LayerNorm (bf16 LN output + bf16 cast of raw x) ----------------
__global__ void ln_kernel(const float* __restrict__ x, const float* __restrict__ g,
                          const float* __restrict__ beta, ushort_t* __restrict__ xn,
                          ushort_t* __restrict__ xb) {
    int row = blockIdx.x;
    int tid = threadIdx.x;
    const float* xr = x + (size_t)row * DMODEL;
    float v0 = xr[tid], v1 = xr[tid + 256], v2 = xr[tid + 512];
    __shared__ float red[4];
    __shared__ float bc;
    float s = v0 + v1 + v2;
#pragma unroll
    for (int o = 32; o > 0; o >>= 1) s += __shfl_down(s, o);
    if ((tid & 63) == 0) red[tid >> 6] = s;
    __syncthreads();
    if (tid == 0) bc = (red[0] + red[1] + red[2] + red[3]) * (1.0f / DMODEL);
    __syncthreads();
    float mu = bc;
    float d0 = v0 - mu, d1 = v1 - mu, d2 = v2 - mu;
    float vs = d0 * d0 + d1 * d1 + d2 * d2;
    __syncthreads();
#pragma unroll
    for (int o = 32; o > 0; o >>= 1) vs += __shfl_down(vs, o);
    if ((tid & 63) == 0) red[tid >> 6] = vs;
    __syncthreads();
    if (tid == 0) bc = rsqrtf((red[0] + red[1] + red[2] + red[3]) * (1.0f / DMODEL) + 1e-5f);
    __syncthreads();
    float r = bc;
    ushort_t* xo = xn + (size_t)row * DMODEL;
    ushort_t* xc = xb + (size_t)row * DMODEL;
    xo[tid]       = f2b(d0 * r * g[tid]       + beta[tid]);
    xo[tid + 256] = f2b(d1 * r * g[tid + 256] + beta[tid + 256]);
    xo[tid + 512] = f2b(d2 * r * g[tid + 512] + beta[tid + 512]);
    xc[tid]       = f2b(v0);
    xc[tid + 256] = f2b(v1);
    xc[tid + 512] = f2b(v2);
}

// ---------------- fused transpose+convert of all 4 weights ----------------
// job z: W[K=768][N_z] f32 -> Wt[N_z][768] bf16
__global__ void transpose_all_kernel(const float* __restrict__ Wq, ushort_t* __restrict__ Tq,
                                     const float* __restrict__ Ws, const float* __restrict__ Wc,
                                     ushort_t* __restrict__ Tsc,
                                     const float* __restrict__ Wp, ushort_t* __restrict__ Tp) {
    const float* W; ushort_t* Wt; int N;
    switch (blockIdx.z) {
        case 0: W = Wq; Wt = Tq;                        N = 2304; break;
        case 1: W = Ws; Wt = Tsc;                       N = 1536; break;
        case 2: W = Wc; Wt = Tsc + (size_t)1536 * 768;  N = 1536; break;
        default: W = Wp; Wt = Tp;                       N = 768;  break;
    }
    int nbase = blockIdx.x * 32;
    if (nbase >= N) return;
    __shared__ float tile[32][33];
    int tid = threadIdx.x;
    int tr = tid >> 5, tc = tid & 31;
    int kbase = blockIdx.y * 32;
#pragma unroll
    for (int p = 0; p < 4; p++) {
        int r = p * 8 + tr;
        tile[r][tc] = W[(size_t)(kbase + r) * N + nbase + tc];
    }
    __syncthreads();
#pragma unroll
    for (int p = 0; p < 4; p++) {
        int r = p * 8 + tr;
        Wt[(size_t)(nbase + r) * 768 + kbase + tc] = f2b(tile[tc][r]);
    }
}

// ---------------- bf16 MFMA GEMM: C[M,N] = A[M,K] @ Bt[N,K]^T + bias ----------------
// 128x128 tile, BK=32, 256 threads (4 waves, 2x2), async global->LDS staging.
__global__ __launch_bounds__(256) void gemm_mfma_kernel(
    const ushort_t* __restrict__ A, const ushort_t* __restrict__ Bt,
    const float* __restrict__ bias, float* __restrict__ C,
    int N, int K) {
    __shared__ ushort_t As[128 * 32];
    __shared__ ushort_t Bs[128 * 32];
    int tid = threadIdx.x;
    int wave = tid >> 6, lane = tid & 63;
    int wm = (wave >> 1) * 64, wn = (wave & 1) * 64;
    int quad = lane >> 4, l16 = lane & 15;
    int m0 = blockIdx.y * 128, n0 = blockIdx.x * 128;

    // staging addresses: chunk = p*256 + tid; LDS offset = chunk*16B (contiguous in tid)
    int r0 = tid >> 2;             // row for p=0
    int kc = (tid & 3) * 8;        // k element offset
    const ushort_t* Ag0 = A + (size_t)(m0 + r0) * K + kc;
    const ushort_t* Ag1 = A + (size_t)(m0 + 64 + r0) * K + kc;
    const ushort_t* Bg0 = Bt + (size_t)(n0 + r0) * K + kc;
    const ushort_t* Bg1 = Bt + (size_t)(n0 + 64 + r0) * K + kc;
    ushort_t* Al0 = &As[(wave * 64) * 8];
    ushort_t* Al1 = &As[(256 + wave * 64) * 8];
    ushort_t* Bl0 = &Bs[(wave * 64) * 8];
    ushort_t* Bl1 = &Bs[(256 + wave * 64) * 8];

    float4v acc[4][4];
#pragma unroll
    for (int i = 0; i < 4; i++)
#pragma unroll
        for (int j = 0; j < 4; j++)
#pragma unroll
            for (int r = 0; r < 4; r++) acc[i][j][r] = 0.0f;

    for (int k0 = 0; k0 < K; k0 += 32) {
        gl_lds16(Ag0 + k0, Al0);
        gl_lds16(Ag1 + k0, Al1);
        gl_lds16(Bg0 + k0, Bl0);
        gl_lds16(Bg1 + k0, Bl1);
        __syncthreads();
        short8 af[4], bf[4];
#pragma unroll
        for (int i = 0; i < 4; i++) af[i] = *(const short8*)&As[(wm + i * 16 + l16) * 32 + quad * 8];
#pragma unroll
        for (int j = 0; j < 4; j++) bf[j] = *(const short8*)&Bs[(wn + j * 16 + l16) * 32 + quad * 8];
#pragma unroll
        for (int i = 0; i < 4; i++)
#pragma unroll
            for (int j = 0; j < 4; j++)
                acc[i][j] = __builtin_amdgcn_mfma_f32_16x16x32_bf16(af[i], bf[j], acc[i][j], 0, 0, 0);
        __syncthreads();
    }
#pragma unroll
    for (int i = 0; i < 4; i++) {
#pragma unroll
        for (int j = 0; j < 4; j++) {
            int col = n0 + wn + j * 16 + l16;
            float bv = bias[col];
#pragma unroll
            for (int r = 0; r < 4; r++) {
                int row = m0 + wm + i * 16 + quad * 4 + r;
                C[(size_t)row * N + col] = acc[i][j][r] + bv;
            }
        }
    }
}

// ---------------- gate + feature map (elementwise over L*D) ----------------
__device__ __forceinline__ float softplus_f(float x) {
    return (x > 15.f) ? x : log1pf(expf(x));
}

// semctx: [L][3072] = [sem_amp | sem_phase | ctx_amp | ctx_phase]
__global__ void gate_feat_kernel(const float* __restrict__ qkv, const float* __restrict__ semctx,
                                 float* __restrict__ qf, float* __restrict__ kf) {
    int idx = blockIdx.x * 256 + threadIdx.x;   // < L*D exactly
    int l = idx / DMODEL, d = idx - l * DMODEL;
    size_t sbase = (size_t)l * 3072;
    float sa = semctx[sbase + d], sp = semctx[sbase + 768 + d];
    float ca = semctx[sbase + 1536 + d], cp = semctx[sbase + 2304 + d];
    float amp = softplus_f(sa) * softplus_f(ca);
    float t = amp * cosf(sp - cp);
    float gate = 1.0f / (1.0f + expf(-t));
    size_t qbase = (size_t)l * (3 * DMODEL);
    float q = qkv[qbase + d];
    float k = qkv[qbase + DMODEL + d] * gate;
    qf[idx] = (q > 0.f) ? q + 1.0f : expf(q);   // elu(q)+1
    kf[idx] = (k > 0.f) ? k + 1.0f : expf(k);   // elu(k)+1
}

// ---------------- per-(head,chunk) KV state sums ----------------
__global__ void chunk_sum_kernel(const float* __restrict__ kf, const float* __restrict__ qkv,
                                 float* __restrict__ S) {
    int h = blockIdx.x % NHEAD;
    int c = blockIdx.x / NHEAD;
    __shared__ float ks[64][64];
    __shared__ float vs[64][64];
    int tid = threadIdx.x;
#pragma unroll
    for (int it = 0; it < 4; it++) {
        int r = it * 16 + (tid >> 4);
        int cc = (tid & 15) * 4;
        int lg = c * 64 + r;
        *(float4*)&ks[r][cc] = *(const float4*)&kf[(size_t)lg * DMODEL + h * DHEAD + cc];
        *(float4*)&vs[r][cc] = *(const float4*)&qkv[(size_t)lg * (3 * DMODEL) + 2 * DMODEL + h * DHEAD + cc];
    }
    __syncthreads();
    int d = tid >> 2;
    int e0 = (tid & 3) * 16;
    float acc[16] = {};
    float ksum = 0.f;
    for (int l = 0; l < 64; l++) {
        float kd = ks[l][d];
        ksum += kd;
#pragma unroll
        for (int u = 0; u < 16; u++) acc[u] += kd * vs[l][e0 + u];
    }
    float* Sp = S + ((size_t)(h * NCHUNK + c)) * 4160;
#pragma unroll
    for (int u = 0; u < 16; u++) Sp[d * 64 + e0 + u] = acc[u];
    if ((tid & 3) == 0) Sp[4096 + d] = ksum;
}

// ---------------- exclusive prefix over chunks ----------------
__global__ void prefix_kernel(const float* __restrict__ S, float* __restrict__ P) {
    int h = blockIdx.x;
    int i = blockIdx.y * 256 + threadIdx.x;
    if (i >= 4160) return;
    float run = 0.f;
    for (int c = 0; c < NCHUNK; c++) {
        size_t off = ((size_t)(h * NCHUNK + c)) * 4160 + i;
        float v = S[off];
        P[off] = run;
        run += v;
    }
}

// ---------------- per-(head,chunk) output (bf16 attn out) ----------------
__global__ void attn_out_kernel(const float* __restrict__ qf, const float* __restrict__ kfb,
                                const float* __restrict__ qkv, const float* __restrict__ P,
                                ushort_t* __restrict__ attn) {
    int h = blockIdx.x % NHEAD;
    int c = blockIdx.x / NHEAD;
    __shared__ float qs[64][64];
    __shared__ float b1[64][64];   // stage1: P tile; stage2: K tile
    __shared__ float b2[64][64];   // stage1: kp (row 0); stage2: V tile
    int tid = threadIdx.x;
    const size_t pbase = ((size_t)(h * NCHUNK + c)) * 4160;
#pragma unroll
    for (int it = 0; it < 4; it++) {
        int r = it * 16 + (tid >> 4);
        int cc = (tid & 15) * 4;
        int lg = c * 64 + r;
        *(float4*)&qs[r][cc] = *(const float4*)&qf[(size_t)lg * DMODEL + h * DHEAD + cc];
        *(float4*)&b1[r][cc] = *(const float4*)&P[pbase + r * 64 + cc];
    }
    if (tid < 16) *(float4*)&b2[0][tid * 4] = *(const float4*)&P[pbase + 4096 + tid * 4];
    __syncthreads();
    int l = tid >> 2;
    int e0 = (tid & 3) * 16;
    float qreg[64];
#pragma unroll
    for (int d = 0; d < 64; d++) qreg[d] = qs[l][d];
    float num[16] = {};
    float den = 1e-6f;   // DEN_EPS
    for (int d = 0; d < 64; d++) {
        float qd = qreg[d];
        den += qd * b2[0][d];
#pragma unroll
        for (int u = 0; u < 16; u++) num[u] += qd * b1[d][e0 + u];
    }
    __syncthreads();
#pragma unroll
    for (int it = 0; it < 4; it++) {
        int r = it * 16 + (tid >> 4);
        int cc = (tid & 15) * 4;
        int lg = c * 64 + r;
        *(float4*)&b1[r][cc] = *(const float4*)&kfb[(size_t)lg * DMODEL + h * DHEAD + cc];
        *(float4*)&b2[r][cc] = *(const float4*)&qkv[(size_t)lg * (3 * DMODEL) + 2 * DMODEL + h * DHEAD + cc];
    }
    __syncthreads();
    for (int j = 0; j <= l; j++) {
        float a = 0.f;
#pragma unroll
        for (int d = 0; d < 64; d++) a += qreg[d] * b1[j][d];
        den += a;
#pragma unroll
        for (int u = 0; u < 16; u++) num[u] += a * b2[j][e0 + u];
    }
    float inv = 1.0f / den;
    ushort_t ob[16];
#pragma unroll
    for (int u = 0; u < 16; u++) ob[u] = f2b(num[u] * inv);
    ushort_t* op = attn + (size_t)(c * 64 + l) * DMODEL + h * DHEAD + e0;
    *(uint4*)&op[0] = *(uint4*)&ob[0];
    *(uint4*)&op[8] = *(uint4*)&ob[8];
}

extern "C" void kernel_launch(void* const* d_in, const int* in_sizes, int n_in,
                              void* d_out, int out_size, void* d_ws, size_t ws_size,
                              hipStream_t stream) {
    const float* x      = (const float*)d_in[0];
    const float* W_qkv  = (const float*)d_in[1];
    const float* b_qkv  = (const float*)d_in[2];
    const float* W_sem  = (const float*)d_in[3];
    const float* b_sem  = (const float*)d_in[4];
    const float* W_ctx  = (const float*)d_in[5];
    const float* b_ctx  = (const float*)d_in[6];
    const float* W_proj = (const float*)d_in[7];
    const float* b_proj = (const float*)d_in[8];
    const float* ln_g   = (const float*)d_in[9];
    const float* ln_b   = (const float*)d_in[10];
    float* out = (float*)d_out;
    float* ws  = (float*)d_ws;

    // ---- workspace layout (float offsets), total 15,728,640 floats = 62.9 MB ----
    ushort_t* Wt_qkv  = (ushort_t*)(ws);                       // 2304*768 us (884736 f)
    ushort_t* Wt_proj = (ushort_t*)(ws + 884736);              // 768*768 us (294912 f)
    float* qkv    = ws + 1572864;                              // 2048*2304 f
    float* semctx = ws + 6291456;                              // 2048*3072 f
    float* qf     = ws + 12582912;                             // 2048*768 f
    float* kf     = ws + 14155776;                             // 2048*768 f
    // overlays:
    ushort_t* xb        = (ushort_t*)qf;                       // 393216 f; dead before gate_feat writes qf
    ushort_t* Wt_semctx = (ushort_t*)(qf + 393216);            // 3072*768 us = 1179648 f (ends at kf)
    ushort_t* xnb       = (ushort_t*)kf;                       // 393216 f; dead after qkv GEMM
    float* S  = semctx;                                        // 12*32*4160 = 1597440 f (semctx dead)
    float* Px = semctx + 1597440;                              // 1597440 f
    ushort_t* attnb = (ushort_t*)semctx;                       // S dead during attn_out; Px disjoint

    // bias for merged sem|ctx GEMM: need contiguous 3072 floats. b_sem and b_ctx are
    // separate inputs; stage a merged copy at end of ws (async d2d copies).
    float* b_semctx = ws + 15725568;                           // 3072 f (tail of ws)
    hipMemcpyAsync(b_semctx,        b_sem, 1536 * sizeof(float), hipMemcpyDeviceToDevice, stream);
    hipMemcpyAsync(b_semctx + 1536, b_ctx, 1536 * sizeof(float), hipMemcpyDeviceToDevice, stream);

    ln_kernel<<<LSEQ, 256, 0, stream>>>(x, ln_g, ln_b, xnb, xb);
    transpose_all_kernel<<<dim3(72, 24, 4), 256, 0, stream>>>(W_qkv, Wt_qkv, W_sem, W_ctx,
                                                              Wt_semctx, W_proj, Wt_proj);

    gemm_mfma_kernel<<<dim3(2304 / 128, LSEQ / 128), 256, 0, stream>>>(xnb, Wt_qkv, b_qkv, qkv, 2304, 768);
    gemm_mfma_kernel<<<dim3(3072 / 128, LSEQ / 128), 256, 0, stream>>>(xb, Wt_semctx, b_semctx, semctx, 3072, 768);

    gate_feat_kernel<<<(LSEQ * DMODEL) / 256, 256, 0, stream>>>(qkv, semctx, qf, kf);
    chunk_sum_kernel<<<NHEAD * NCHUNK, 256, 0, stream>>>(kf, qkv, S);
    prefix_kernel<<<dim3(NHEAD, 17), 256, 0, stream>>>(S, Px);
    attn_out_kernel<<<NHEAD * NCHUNK, 256, 0, stream>>>(qf, kf, qkv, Px, attnb);

    gemm_mfma_kernel<<<dim3(768 / 128, LSEQ / 128), 256, 0, stream>>>(attnb, Wt_proj, b_proj, out, 768, 768);
}

// Round 5
// 196.371 us; speedup vs baseline: 2.4958x; 1.1608x over previous
//
#include <hip/hip_runtime.h>
#include <math.h>

#define LSEQ 2048
#define DMODEL 768
#define NHEAD 12
#define DHEAD 64
#define NCHUNK 32   // 2048 / 64
#define CSIZE 64
#define NMERGED 5376   // 2304 qkv | 1536 sem | 1536 ctx

typedef unsigned short ushort_t;
typedef __attribute__((ext_vector_type(8))) short short8;
typedef float float4v __attribute__((ext_vector_type(4)));

__device__ __forceinline__ ushort_t f2b(float f) {
    union { float f; unsigned int u; } v; v.f = f;
    unsigned int u = v.u;
    return (ushort_t)((u + 0x7fffu + ((u >> 16) & 1u)) >> 16);
}
__device__ __forceinline__ float b2f(ushort_t u) {
    union { unsigned int u; float f; } v; v.u = ((unsigned int)u) << 16;
    return v.f;
}

// async 16B global->LDS (wave-uniform LDS base + lane*16)
__device__ __forceinline__ void gl_lds16(const ushort_t* g, ushort_t* l) {
    __builtin_amdgcn_global_load_lds(
        (const __attribute__((address_space(1))) unsigned int*)g,
        (__attribute__((address_space(3))) unsigned int*)l, 16, 0, 0);
}

// ---------------- LayerNorm (bf16 LN output + bf16 cast of raw x) ----------------
__global__ void ln_kernel(const float* __restrict__ x, const float* __restrict__ g,
                          const float* __restrict__ beta, ushort_t* __restrict__ xn,
                          ushort_t* __restrict__ xb) {
    int row = blockIdx.x;
    int tid = threadIdx.x;
    const float* xr = x + (size_t)row * DMODEL;
    float v0 = xr[tid], v1 = xr[tid + 256], v2 = xr[tid + 512];
    __shared__ float red[4];
    __shared__ float bc;
    float s = v0 + v1 + v2;
#pragma unroll
    for (int o = 32; o > 0; o >>= 1) s += __shfl_down(s, o);
    if ((tid & 63) == 0) red[tid >> 6] = s;
    __syncthreads();
    if (tid == 0) bc = (red[0] + red[1] + red[2] + red[3]) * (1.0f / DMODEL);
    __syncthreads();
    float mu = bc;
    float d0 = v0 - mu, d1 = v1 - mu, d2 = v2 - mu;
    float vs = d0 * d0 + d1 * d1 + d2 * d2;
    __syncthreads();
#pragma unroll
    for (int o = 32; o > 0; o >>= 1) vs += __shfl_down(vs, o);
    if ((tid & 63) == 0) red[tid >> 6] = vs;
    __syncthreads();
    if (tid == 0) bc = rsqrtf((red[0] + red[1] + red[2] + red[3]) * (1.0f / DMODEL) + 1e-5f);
    __syncthreads();
    float r = bc;
    ushort_t* xo = xn + (size_t)row * DMODEL;
    ushort_t* xc = xb + (size_t)row * DMODEL;
    xo[tid]       = f2b(d0 * r * g[tid]       + beta[tid]);
    xo[tid + 256] = f2b(d1 * r * g[tid + 256] + beta[tid + 256]);
    xo[tid + 512] = f2b(d2 * r * g[tid + 512] + beta[tid + 512]);
    xc[tid]       = f2b(v0);
    xc[tid + 256] = f2b(v1);
    xc[tid + 512] = f2b(v2);
}

// ---------------- fused transpose+convert of all 4 weights ----------------
__global__ void transpose_all_kernel(const float* __restrict__ Wq, const float* __restrict__ Ws,
                                     const float* __restrict__ Wc, ushort_t* __restrict__ Tm,
                                     const float* __restrict__ Wp, ushort_t* __restrict__ Tp) {
    const float* W; ushort_t* Wt; int N;
    switch (blockIdx.z) {
        case 0: W = Wq; Wt = Tm;                        N = 2304; break;
        case 1: W = Ws; Wt = Tm + (size_t)2304 * 768;   N = 1536; break;
        case 2: W = Wc; Wt = Tm + (size_t)3840 * 768;   N = 1536; break;
        default: W = Wp; Wt = Tp;                       N = 768;  break;
    }
    int nbase = blockIdx.x * 32;
    if (nbase >= N) return;
    __shared__ float tile[32][33];
    int tid = threadIdx.x;
    int tr = tid >> 5, tc = tid & 31;
    int kbase = blockIdx.y * 32;
#pragma unroll
    for (int p = 0; p < 4; p++) {
        int r = p * 8 + tr;
        tile[r][tc] = W[(size_t)(kbase + r) * N + nbase + tc];
    }
    __syncthreads();
#pragma unroll
    for (int p = 0; p < 4; p++) {
        int r = p * 8 + tr;
        Wt[(size_t)(nbase + r) * 768 + kbase + tc] = f2b(tile[tc][r]);
    }
}

// ---------------- merged bf16 MFMA GEMM: C[M,5376], A chosen per column block ----------------
__global__ __launch_bounds__(256) void gemm_merged_kernel(
    const ushort_t* __restrict__ Axn, const ushort_t* __restrict__ Axb,
    const ushort_t* __restrict__ Bt,
    const float* __restrict__ b_qkv, const float* __restrict__ b_sem,
    const float* __restrict__ b_ctx, float* __restrict__ C) {
    const int K = 768, N = NMERGED;
    __shared__ ushort_t As[128 * 32];
    __shared__ ushort_t Bs[128 * 32];
    int tid = threadIdx.x;
    int wave = tid >> 6, lane = tid & 63;
    int wm = (wave >> 1) * 64, wn = (wave & 1) * 64;
    int quad = lane >> 4, l16 = lane & 15;
    int m0 = blockIdx.y * 128, n0 = blockIdx.x * 128;
    const ushort_t* A = (n0 < 2304) ? Axn : Axb;
    const float* bias = (n0 < 2304) ? (b_qkv + n0) : (n0 < 3840 ? (b_sem + n0 - 2304) : (b_ctx + n0 - 3840));

    int r0 = tid >> 2;
    int kc = (tid & 3) * 8;
    const ushort_t* Ag0 = A + (size_t)(m0 + r0) * K + kc;
    const ushort_t* Ag1 = A + (size_t)(m0 + 64 + r0) * K + kc;
    const ushort_t* Bg0 = Bt + (size_t)(n0 + r0) * K + kc;
    const ushort_t* Bg1 = Bt + (size_t)(n0 + 64 + r0) * K + kc;
    ushort_t* Al0 = &As[(wave * 64) * 8];
    ushort_t* Al1 = &As[(256 + wave * 64) * 8];
    ushort_t* Bl0 = &Bs[(wave * 64) * 8];
    ushort_t* Bl1 = &Bs[(256 + wave * 64) * 8];

    float4v acc[4][4];
#pragma unroll
    for (int i = 0; i < 4; i++)
#pragma unroll
        for (int j = 0; j < 4; j++)
#pragma unroll
            for (int r = 0; r < 4; r++) acc[i][j][r] = 0.0f;

    for (int k0 = 0; k0 < K; k0 += 32) {
        gl_lds16(Ag0 + k0, Al0);
        gl_lds16(Ag1 + k0, Al1);
        gl_lds16(Bg0 + k0, Bl0);
        gl_lds16(Bg1 + k0, Bl1);
        __syncthreads();
        short8 af[4], bf[4];
#pragma unroll
        for (int i = 0; i < 4; i++) af[i] = *(const short8*)&As[(wm + i * 16 + l16) * 32 + quad * 8];
#pragma unroll
        for (int j = 0; j < 4; j++) bf[j] = *(const short8*)&Bs[(wn + j * 16 + l16) * 32 + quad * 8];
#pragma unroll
        for (int i = 0; i < 4; i++)
#pragma unroll
            for (int j = 0; j < 4; j++)
                acc[i][j] = __builtin_amdgcn_mfma_f32_16x16x32_bf16(af[i], bf[j], acc[i][j], 0, 0, 0);
        __syncthreads();
    }
#pragma unroll
    for (int i = 0; i < 4; i++) {
#pragma unroll
        for (int j = 0; j < 4; j++) {
            int colb = wn + j * 16 + l16;
            float bv = bias[colb];
#pragma unroll
            for (int r = 0; r < 4; r++) {
                int row = m0 + wm + i * 16 + quad * 4 + r;
                C[(size_t)row * N + n0 + colb] = acc[i][j][r] + bv;
            }
        }
    }
}

// ---------------- 64x64-tile bf16 MFMA GEMM (proj: N=768) ----------------
__global__ __launch_bounds__(256) void gemm_64_kernel(
    const ushort_t* __restrict__ A, const ushort_t* __restrict__ Bt,
    const float* __restrict__ bias, float* __restrict__ C,
    int N, int K) {
    __shared__ ushort_t As[64 * 32];
    __shared__ ushort_t Bs[64 * 32];
    int tid = threadIdx.x;
    int wave = tid >> 6, lane = tid & 63;
    int wm = (wave >> 1) * 32, wn = (wave & 1) * 32;
    int quad = lane >> 4, l16 = lane & 15;
    int m0 = blockIdx.y * 64, n0 = blockIdx.x * 64;

    int r0 = tid >> 2;
    int kc = (tid & 3) * 8;
    const ushort_t* Ag = A + (size_t)(m0 + r0) * K + kc;
    const ushort_t* Bg = Bt + (size_t)(n0 + r0) * K + kc;
    ushort_t* Al = &As[(wave * 16) * 32];
    ushort_t* Bl = &Bs[(wave * 16) * 32];

    float4v acc[2][2];
#pragma unroll
    for (int i = 0; i < 2; i++)
#pragma unroll
        for (int j = 0; j < 2; j++)
#pragma unroll
            for (int r = 0; r < 4; r++) acc[i][j][r] = 0.0f;

    for (int k0 = 0; k0 < K; k0 += 32) {
        gl_lds16(Ag + k0, Al);
        gl_lds16(Bg + k0, Bl);
        __syncthreads();
        short8 af[2], bf[2];
#pragma unroll
        for (int i = 0; i < 2; i++) af[i] = *(const short8*)&As[(wm + i * 16 + l16) * 32 + quad * 8];
#pragma unroll
        for (int j = 0; j < 2; j++) bf[j] = *(const short8*)&Bs[(wn + j * 16 + l16) * 32 + quad * 8];
#pragma unroll
        for (int i = 0; i < 2; i++)
#pragma unroll
            for (int j = 0; j < 2; j++)
                acc[i][j] = __builtin_amdgcn_mfma_f32_16x16x32_bf16(af[i], bf[j], acc[i][j], 0, 0, 0);
        __syncthreads();
    }
#pragma unroll
    for (int i = 0; i < 2; i++) {
#pragma unroll
        for (int j = 0; j < 2; j++) {
            int col = n0 + wn + j * 16 + l16;
            float bv = bias[col];
#pragma unroll
            for (int r = 0; r < 4; r++) {
                int row = m0 + wm + i * 16 + quad * 4 + r;
                C[(size_t)row * N + col] = acc[i][j][r] + bv;
            }
        }
    }
}

// ---------------- gate + feature map -> bf16 qf/kf (4 elems/thread) ----------------
__device__ __forceinline__ float softplus_f(float x) {
    return (x > 15.f) ? x : log1pf(expf(x));
}

__global__ void gate_feat_kernel(const float* __restrict__ qsc,
                                 ushort_t* __restrict__ qf, ushort_t* __restrict__ kf) {
    int t = blockIdx.x * 256 + threadIdx.x;      // t < L*D/4 = 393216
    int l = t / 192, d = (t - l * 192) * 4;
    size_t base = (size_t)l * NMERGED;
    float sa[4], sp[4], ca[4], cp[4], q[4], k[4];
    *(float4*)sa = *(const float4*)&qsc[base + 2304 + d];
    *(float4*)sp = *(const float4*)&qsc[base + 3072 + d];
    *(float4*)ca = *(const float4*)&qsc[base + 3840 + d];
    *(float4*)cp = *(const float4*)&qsc[base + 4608 + d];
    *(float4*)q  = *(const float4*)&qsc[base + d];
    *(float4*)k  = *(const float4*)&qsc[base + 768 + d];
    ushort_t qo[4], ko[4];
#pragma unroll
    for (int j = 0; j < 4; j++) {
        float amp = softplus_f(sa[j]) * softplus_f(ca[j]);
        float tt = amp * cosf(sp[j] - cp[j]);
        float gate = 1.0f / (1.0f + expf(-tt));
        float kv = k[j] * gate;
        float qv = q[j];
        qo[j] = f2b((qv > 0.f) ? qv + 1.0f : expf(qv));
        ko[j] = f2b((kv > 0.f) ? kv + 1.0f : expf(kv));
    }
    size_t o = (size_t)l * DMODEL + d;
    *(uint2*)&qf[o] = *(uint2*)qo;
    *(uint2*)&kf[o] = *(uint2*)ko;
}

// ---------------- per-(head,chunk) KV state sums (kf is bf16) ----------------
__global__ void chunk_sum_kernel(const ushort_t* __restrict__ kf, const float* __restrict__ qsc,
                                 float* __restrict__ S) {
    int h = blockIdx.x % NHEAD;
    int c = blockIdx.x / NHEAD;
    __shared__ float ks[64][64];
    __shared__ float vs[64][64];
    int tid = threadIdx.x;
#pragma unroll
    for (int it = 0; it < 4; it++) {
        int r = it * 16 + (tid >> 4);
        int cc = (tid & 15) * 4;
        int lg = c * 64 + r;
        ushort_t kt[4];
        *(uint2*)kt = *(const uint2*)&kf[(size_t)lg * DMODEL + h * DHEAD + cc];
        ks[r][cc + 0] = b2f(kt[0]); ks[r][cc + 1] = b2f(kt[1]);
        ks[r][cc + 2] = b2f(kt[2]); ks[r][cc + 3] = b2f(kt[3]);
        *(float4*)&vs[r][cc] = *(const float4*)&qsc[(size_t)lg * NMERGED + 1536 + h * DHEAD + cc];
    }
    __syncthreads();
    int d = tid >> 2;
    int e0 = (tid & 3) * 16;
    float acc[16] = {};
    float ksum = 0.f;
    for (int l = 0; l < 64; l++) {
        float kd = ks[l][d];
        ksum += kd;
#pragma unroll
        for (int u = 0; u < 16; u++) acc[u] += kd * vs[l][e0 + u];
    }
    float* Sp = S + ((size_t)(h * NCHUNK + c)) * 4160;
#pragma unroll
    for (int u = 0; u < 16; u++) Sp[d * 64 + e0 + u] = acc[u];
    if ((tid & 3) == 0) Sp[4096 + d] = ksum;
}

// ---------------- exclusive prefix over chunks (in-place on S) ----------------
__global__ void prefix_kernel(float* __restrict__ S) {
    int h = blockIdx.x;
    int i = blockIdx.y * 256 + threadIdx.x;
    if (i >= 4160) return;
    float run = 0.f;
    for (int c = 0; c < NCHUNK; c++) {
        size_t off = ((size_t)(h * NCHUNK + c)) * 4160 + i;
        float v = S[off];
        S[off] = run;
        run += v;
    }
}

// ---------------- per-(head,chunk) output (bf16 qf/kf in, bf16 attn out) ----------------
__global__ void attn_out_kernel(const ushort_t* __restrict__ qf, const ushort_t* __restrict__ kfb,
                                const float* __restrict__ qsc, const float* __restrict__ P,
                                ushort_t* __restrict__ attn) {
    int h = blockIdx.x % NHEAD;
    int c = blockIdx.x / NHEAD;
    __shared__ float qs[64][64];
    __shared__ float b1[64][64];   // stage1: P tile; stage2: K tile
    __shared__ float b2[64][64];   // stage1: kp (row 0); stage2: V tile
    int tid = threadIdx.x;
    const size_t pbase = ((size_t)(h * NCHUNK + c)) * 4160;
#pragma unroll
    for (int it = 0; it < 4; it++) {
        int r = it * 16 + (tid >> 4);
        int cc = (tid & 15) * 4;
        int lg = c * 64 + r;
        ushort_t qt[4];
        *(uint2*)qt = *(const uint2*)&qf[(size_t)lg * DMODEL + h * DHEAD + cc];
        qs[r][cc + 0] = b2f(qt[0]); qs[r][cc + 1] = b2f(qt[1]);
        qs[r][cc + 2] = b2f(qt[2]); qs[r][cc + 3] = b2f(qt[3]);
        *(float4*)&b1[r][cc] = *(const float4*)&P[pbase + r * 64 + cc];
    }
    if (tid < 16) *(float4*)&b2[0][tid * 4] = *(const float4*)&P[pbase + 4096 + tid * 4];
    __syncthreads();
    int l = tid >> 2;
    int e0 = (tid & 3) * 16;
    float qreg[64];
#pragma unroll
    for (int d = 0; d < 64; d++) qreg[d] = qs[l][d];
    float num[16] = {};
    float den = 1e-6f;   // DEN_EPS
    for (int d = 0; d < 64; d++) {
        float qd = qreg[d];
        den += qd * b2[0][d];
#pragma unroll
        for (int u = 0; u < 16; u++) num[u] += qd * b1[d][e0 + u];
    }
    __syncthreads();
#pragma unroll
    for (int it = 0; it < 4; it++) {
        int r = it * 16 + (tid >> 4);
        int cc = (tid & 15) * 4;
        int lg = c * 64 + r;
        ushort_t kt[4];
        *(uint2*)kt = *(const uint2*)&kfb[(size_t)lg * DMODEL + h * DHEAD + cc];
        b1[r][cc + 0] = b2f(kt[0]); b1[r][cc + 1] = b2f(kt[1]);
        b1[r][cc + 2] = b2f(kt[2]); b1[r][cc + 3] = b2f(kt[3]);
        b2[r][cc + 0] = 0.f;  // placeholder to keep write pattern; overwritten below
        *(float4*)&b2[r][cc] = *(const float4*)&qsc[(size_t)lg * NMERGED + 1536 + h * DHEAD + cc];
    }
    __syncthreads();
    for (int j = 0; j <= l; j++) {
        float a = 0.f;
#pragma unroll
        for (int d = 0; d < 64; d++) a += qreg[d] * b1[j][d];
        den += a;
#pragma unroll
        for (int u = 0; u < 16; u++) num[u] += a * b2[j][e0 + u];
    }
    float inv = 1.0f / den;
    ushort_t ob[16];
#pragma unroll
    for (int u = 0; u < 16; u++) ob[u] = f2b(num[u] * inv);
    ushort_t* op = attn + (size_t)(c * 64 + l) * DMODEL + h * DHEAD + e0;
    *(uint4*)&op[0] = *(uint4*)&ob[0];
    *(uint4*)&op[8] = *(uint4*)&ob[8];
}

extern "C" void kernel_launch(void* const* d_in, const int* in_sizes, int n_in,
                              void* d_out, int out_size, void* d_ws, size_t ws_size,
                              hipStream_t stream) {
    const float* x      = (const float*)d_in[0];
    const float* W_qkv  = (const float*)d_in[1];
    const float* b_qkv  = (const float*)d_in[2];
    const float* W_sem  = (const float*)d_in[3];
    const float* b_sem  = (const float*)d_in[4];
    const float* W_ctx  = (const float*)d_in[5];
    const float* b_ctx  = (const float*)d_in[6];
    const float* W_proj = (const float*)d_in[7];
    const float* b_proj = (const float*)d_in[8];
    const float* ln_g   = (const float*)d_in[9];
    const float* ln_b   = (const float*)d_in[10];
    float* out = (float*)d_out;
    float* ws  = (float*)d_ws;

    // ---- workspace layout (float-slot offsets), total 15,728,640 f = 62.9 MB ----
    // NOTE: a 2048x768 bf16 array = 786,432 float-slots (L*D/2). Verified live ranges:
    //   step: 1 ln  2 transpose  3 gemm_merged  4 gate  5 chunk_sum  6 prefix  7 attn_out  8 gemm_64
    ushort_t* Wt_merged = (ushort_t*)(ws);                 // [0, 2064384)        live 2-3
    ushort_t* Wt_proj   = (ushort_t*)(ws + 2064384);       // [2064384, 2359296)  live 2-8
    ushort_t* xb        = (ushort_t*)(ws + 2359296);       // [2359296, 3145728)  live 1-3
    ushort_t* xnb       = (ushort_t*)(ws + 3145728);       // [3145728, 3932160)  live 1-3
    float*    qsc       = ws + 3932160;                    // [3932160, 14942208) live 3-7
    ushort_t* qf        = (ushort_t*)(ws + 14942208);      // [14942208, 15728640) live 4-7
    ushort_t* kf        = (ushort_t*)(ws + 3145728);       // overlays xnb (dead after 3), live 4-7
    float*    S         = ws;                              // [0, 1597440) overlays Wt_merged (dead after 3), live 5-7
    ushort_t* attnb     = (ushort_t*)(ws + 2359296);       // overlays xb (dead after 3), live 7-8

    ln_kernel<<<LSEQ, 256, 0, stream>>>(x, ln_g, ln_b, xnb, xb);
    transpose_all_kernel<<<dim3(72, 24, 4), 256, 0, stream>>>(W_qkv, W_sem, W_ctx, Wt_merged,
                                                              W_proj, Wt_proj);

    gemm_merged_kernel<<<dim3(NMERGED / 128, LSEQ / 128), 256, 0, stream>>>(
        xnb, xb, Wt_merged, b_qkv, b_sem, b_ctx, qsc);

    gate_feat_kernel<<<(LSEQ * DMODEL / 4) / 256, 256, 0, stream>>>(qsc, qf, kf);
    chunk_sum_kernel<<<NHEAD * NCHUNK, 256, 0, stream>>>(kf, qsc, S);
    prefix_kernel<<<dim3(NHEAD, 17), 256, 0, stream>>>(S);
    attn_out_kernel<<<NHEAD * NCHUNK, 256, 0, stream>>>(qf, kf, qsc, S, attnb);

    gemm_64_kernel<<<dim3(768 / 64, LSEQ / 64), 256, 0, stream>>>(attnb, Wt_proj, b_proj, out, 768, 768);
}

// Round 7
// 163.432 us; speedup vs baseline: 2.9988x; 1.2015x over previous
//
#include <hip/hip_runtime.h>
#include <math.h>

#define LSEQ 2048
#define DMODEL 768
#define NHEAD 12
#define DHEAD 64
#define NCHUNK 32   // 2048 / 64
#define NMERGED 5376   // 2304 qkv | 1536 sem | 1536 ctx

typedef unsigned short ushort_t;
typedef __attribute__((ext_vector_type(8))) short short8;
typedef float float4v __attribute__((ext_vector_type(4)));

__device__ __forceinline__ ushort_t f2b(float f) {
    union { float f; unsigned int u; } v; v.f = f;
    unsigned int u = v.u;
    return (ushort_t)((u + 0x7fffu + ((u >> 16) & 1u)) >> 16);
}
__device__ __forceinline__ float b2f(ushort_t u) {
    union { unsigned int u; float f; } v; v.u = ((unsigned int)u) << 16;
    return v.f;
}

// async 16B global->LDS (wave-uniform LDS base + lane*16)
__device__ __forceinline__ void gl_lds16(const ushort_t* g, ushort_t* l) {
    __builtin_amdgcn_global_load_lds(
        (const __attribute__((address_space(1))) unsigned int*)g,
        (__attribute__((address_space(3))) unsigned int*)l, 16, 0, 0);
}

// ---------------- LayerNorm (bf16 LN output + bf16 cast of raw x) ----------------
__global__ void ln_kernel(const float* __restrict__ x, const float* __restrict__ g,
                          const float* __restrict__ beta, ushort_t* __restrict__ xn,
                          ushort_t* __restrict__ xb) {
    int row = blockIdx.x;
    int tid = threadIdx.x;
    const float* xr = x + (size_t)row * DMODEL;
    float v0 = xr[tid], v1 = xr[tid + 256], v2 = xr[tid + 512];
    __shared__ float red[4];
    __shared__ float bc;
    float s = v0 + v1 + v2;
#pragma unroll
    for (int o = 32; o > 0; o >>= 1) s += __shfl_down(s, o);
    if ((tid & 63) == 0) red[tid >> 6] = s;
    __syncthreads();
    if (tid == 0) bc = (red[0] + red[1] + red[2] + red[3]) * (1.0f / DMODEL);
    __syncthreads();
    float mu = bc;
    float d0 = v0 - mu, d1 = v1 - mu, d2 = v2 - mu;
    float vs = d0 * d0 + d1 * d1 + d2 * d2;
    __syncthreads();
#pragma unroll
    for (int o = 32; o > 0; o >>= 1) vs += __shfl_down(vs, o);
    if ((tid & 63) == 0) red[tid >> 6] = vs;
    __syncthreads();
    if (tid == 0) bc = rsqrtf((red[0] + red[1] + red[2] + red[3]) * (1.0f / DMODEL) + 1e-5f);
    __syncthreads();
    float r = bc;
    ushort_t* xo = xn + (size_t)row * DMODEL;
    ushort_t* xc = xb + (size_t)row * DMODEL;
    xo[tid]       = f2b(d0 * r * g[tid]       + beta[tid]);
    xo[tid + 256] = f2b(d1 * r * g[tid + 256] + beta[tid + 256]);
    xo[tid + 512] = f2b(d2 * r * g[tid + 512] + beta[tid + 512]);
    xc[tid]       = f2b(v0);
    xc[tid + 256] = f2b(v1);
    xc[tid + 512] = f2b(v2);
}

// ---------------- fused transpose+convert of all 4 weights ----------------
__global__ void transpose_all_kernel(const float* __restrict__ Wq, const float* __restrict__ Ws,
                                     const float* __restrict__ Wc, ushort_t* __restrict__ Tm,
                                     const float* __restrict__ Wp, ushort_t* __restrict__ Tp) {
    const float* W; ushort_t* Wt; int N;
    switch (blockIdx.z) {
        case 0: W = Wq; Wt = Tm;                        N = 2304; break;
        case 1: W = Ws; Wt = Tm + (size_t)2304 * 768;   N = 1536; break;
        case 2: W = Wc; Wt = Tm + (size_t)3840 * 768;   N = 1536; break;
        default: W = Wp; Wt = Tp;                       N = 768;  break;
    }
    int nbase = blockIdx.x * 32;
    if (nbase >= N) return;
    __shared__ float tile[32][33];
    int tid = threadIdx.x;
    int tr = tid >> 5, tc = tid & 31;
    int kbase = blockIdx.y * 32;
#pragma unroll
    for (int p = 0; p < 4; p++) {
        int r = p * 8 + tr;
        tile[r][tc] = W[(size_t)(kbase + r) * N + nbase + tc];
    }
    __syncthreads();
#pragma unroll
    for (int p = 0; p < 4; p++) {
        int r = p * 8 + tr;
        Wt[(size_t)(nbase + r) * 768 + kbase + tc] = f2b(tile[tc][r]);
    }
}

// ---------------- merged bf16 MFMA GEMM: C[M,5376]; V block (cols 1536..2304) -> bf16 vb ----------------
__global__ __launch_bounds__(256) void gemm_merged_kernel(
    const ushort_t* __restrict__ Axn, const ushort_t* __restrict__ Axb,
    const ushort_t* __restrict__ Bt,
    const float* __restrict__ b_qkv, const float* __restrict__ b_sem,
    const float* __restrict__ b_ctx, float* __restrict__ C,
    ushort_t* __restrict__ vb) {
    const int K = 768, N = NMERGED;
    __shared__ ushort_t As[128 * 32];
    __shared__ ushort_t Bs[128 * 32];
    int tid = threadIdx.x;
    int wave = tid >> 6, lane = tid & 63;
    int wm = (wave >> 1) * 64, wn = (wave & 1) * 64;
    int quad = lane >> 4, l16 = lane & 15;
    int m0 = blockIdx.y * 128, n0 = blockIdx.x * 128;
    const ushort_t* A = (n0 < 2304) ? Axn : Axb;
    const float* bias = (n0 < 2304) ? (b_qkv + n0) : (n0 < 3840 ? (b_sem + n0 - 2304) : (b_ctx + n0 - 3840));

    int r0 = tid >> 2;
    int kc = (tid & 3) * 8;
    const ushort_t* Ag0 = A + (size_t)(m0 + r0) * K + kc;
    const ushort_t* Ag1 = A + (size_t)(m0 + 64 + r0) * K + kc;
    const ushort_t* Bg0 = Bt + (size_t)(n0 + r0) * K + kc;
    const ushort_t* Bg1 = Bt + (size_t)(n0 + 64 + r0) * K + kc;
    ushort_t* Al0 = &As[(wave * 64) * 8];
    ushort_t* Al1 = &As[(256 + wave * 64) * 8];
    ushort_t* Bl0 = &Bs[(wave * 64) * 8];
    ushort_t* Bl1 = &Bs[(256 + wave * 64) * 8];

    float4v acc[4][4];
#pragma unroll
    for (int i = 0; i < 4; i++)
#pragma unroll
        for (int j = 0; j < 4; j++)
#pragma unroll
            for (int r = 0; r < 4; r++) acc[i][j][r] = 0.0f;

    for (int k0 = 0; k0 < K; k0 += 32) {
        gl_lds16(Ag0 + k0, Al0);
        gl_lds16(Ag1 + k0, Al1);
        gl_lds16(Bg0 + k0, Bl0);
        gl_lds16(Bg1 + k0, Bl1);
        __syncthreads();
        short8 af[4], bf[4];
#pragma unroll
        for (int i = 0; i < 4; i++) af[i] = *(const short8*)&As[(wm + i * 16 + l16) * 32 + quad * 8];
#pragma unroll
        for (int j = 0; j < 4; j++) bf[j] = *(const short8*)&Bs[(wn + j * 16 + l16) * 32 + quad * 8];
#pragma unroll
        for (int i = 0; i < 4; i++)
#pragma unroll
            for (int j = 0; j < 4; j++)
                acc[i][j] = __builtin_amdgcn_mfma_f32_16x16x32_bf16(af[i], bf[j], acc[i][j], 0, 0, 0);
        __syncthreads();
    }
    bool is_v = (n0 >= 1536 && n0 < 2304);   // block-uniform
#pragma unroll
    for (int i = 0; i < 4; i++) {
#pragma unroll
        for (int j = 0; j < 4; j++) {
            int colb = wn + j * 16 + l16;
            float bv = bias[colb];
#pragma unroll
            for (int r = 0; r < 4; r++) {
                int row = m0 + wm + i * 16 + quad * 4 + r;
                float o = acc[i][j][r] + bv;
                if (is_v) {
                    vb[(size_t)row * DMODEL + (n0 - 1536) + colb] = f2b(o);
                } else {
                    C[(size_t)row * N + n0 + colb] = o;
                }
            }
        }
    }
}

// ---------------- 64x64-tile bf16 MFMA GEMM (proj: N=768) ----------------
__global__ __launch_bounds__(256) void gemm_64_kernel(
    const ushort_t* __restrict__ A, const ushort_t* __restrict__ Bt,
    const float* __restrict__ bias, float* __restrict__ C,
    int N, int K) {
    __shared__ ushort_t As[64 * 32];
    __shared__ ushort_t Bs[64 * 32];
    int tid = threadIdx.x;
    int wave = tid >> 6, lane = tid & 63;
    int wm = (wave >> 1) * 32, wn = (wave & 1) * 32;
    int quad = lane >> 4, l16 = lane & 15;
    int m0 = blockIdx.y * 64, n0 = blockIdx.x * 64;

    int r0 = tid >> 2;
    int kc = (tid & 3) * 8;
    const ushort_t* Ag = A + (size_t)(m0 + r0) * K + kc;
    const ushort_t* Bg = Bt + (size_t)(n0 + r0) * K + kc;
    ushort_t* Al = &As[(wave * 16) * 32];
    ushort_t* Bl = &Bs[(wave * 16) * 32];

    float4v acc[2][2];
#pragma unroll
    for (int i = 0; i < 2; i++)
#pragma unroll
        for (int j = 0; j < 2; j++)
#pragma unroll
            for (int r = 0; r < 4; r++) acc[i][j][r] = 0.0f;

    for (int k0 = 0; k0 < K; k0 += 32) {
        gl_lds16(Ag + k0, Al);
        gl_lds16(Bg + k0, Bl);
        __syncthreads();
        short8 af[2], bf[2];
#pragma unroll
        for (int i = 0; i < 2; i++) af[i] = *(const short8*)&As[(wm + i * 16 + l16) * 32 + quad * 8];
#pragma unroll
        for (int j = 0; j < 2; j++) bf[j] = *(const short8*)&Bs[(wn + j * 16 + l16) * 32 + quad * 8];
#pragma unroll
        for (int i = 0; i < 2; i++)
#pragma unroll
            for (int j = 0; j < 2; j++)
                acc[i][j] = __builtin_amdgcn_mfma_f32_16x16x32_bf16(af[i], bf[j], acc[i][j], 0, 0, 0);
        __syncthreads();
    }
#pragma unroll
    for (int i = 0; i < 2; i++) {
#pragma unroll
        for (int j = 0; j < 2; j++) {
            int col = n0 + wn + j * 16 + l16;
            float bv = bias[col];
#pragma unroll
            for (int r = 0; r < 4; r++) {
                int row = m0 + wm + i * 16 + quad * 4 + r;
                C[(size_t)row * N + col] = acc[i][j][r] + bv;
            }
        }
    }
}

// ---------------- gate + feature map -> bf16 qf/kf (4 elems/thread) ----------------
__device__ __forceinline__ float softplus_f(float x) {
    return (x > 15.f) ? x : log1pf(expf(x));
}

__global__ void gate_feat_kernel(const float* __restrict__ qsc,
                                 ushort_t* __restrict__ qf, ushort_t* __restrict__ kf) {
    int t = blockIdx.x * 256 + threadIdx.x;      // t < L*D/4 = 393216
    int l = t / 192, d = (t - l * 192) * 4;
    size_t base = (size_t)l * NMERGED;
    float sa[4], sp[4], ca[4], cp[4], q[4], k[4];
    *(float4*)sa = *(const float4*)&qsc[base + 2304 + d];
    *(float4*)sp = *(const float4*)&qsc[base + 3072 + d];
    *(float4*)ca = *(const float4*)&qsc[base + 3840 + d];
    *(float4*)cp = *(const float4*)&qsc[base + 4608 + d];
    *(float4*)q  = *(const float4*)&qsc[base + d];
    *(float4*)k  = *(const float4*)&qsc[base + 768 + d];
    ushort_t qo[4], ko[4];
#pragma unroll
    for (int j = 0; j < 4; j++) {
        float amp = softplus_f(sa[j]) * softplus_f(ca[j]);
        float tt = amp * cosf(sp[j] - cp[j]);
        float gate = 1.0f / (1.0f + expf(-tt));
        float kv = k[j] * gate;
        float qv = q[j];
        qo[j] = f2b((qv > 0.f) ? qv + 1.0f : expf(qv));
        ko[j] = f2b((kv > 0.f) ? kv + 1.0f : expf(kv));
    }
    size_t o = (size_t)l * DMODEL + d;
    *(uint2*)&qf[o] = *(uint2*)qo;
    *(uint2*)&kf[o] = *(uint2*)ko;
}

// ---------------- per-(head,chunk) KV state sums via MFMA ----------------
// S_t layout per (h,c): [e*64+d] = sum_l k[l][d]*v[l][e]; [4096+d] = ksum[d]
__global__ __launch_bounds__(256) void chunk_sum_mfma(const ushort_t* __restrict__ kf,
                                                      const ushort_t* __restrict__ vb,
                                                      float* __restrict__ S) {
    int h = blockIdx.x % NHEAD;
    int c = blockIdx.x / NHEAD;
    __shared__ ushort_t Kt[64 * 72];   // [d][l]
    __shared__ ushort_t Vt[64 * 72];   // [e][l]
    int tid = threadIdx.x;
    const size_t hb = (size_t)h * DHEAD;
#pragma unroll
    for (int it = 0; it < 4; it++) {
        int r = it * 16 + (tid >> 4);      // sequence pos within chunk
        int cc = (tid & 15) * 4;           // d/e base
        int lg = c * 64 + r;
        ushort_t kt4[4], vt4[4];
        *(uint2*)kt4 = *(const uint2*)&kf[(size_t)lg * DMODEL + hb + cc];
        *(uint2*)vt4 = *(const uint2*)&vb[(size_t)lg * DMODEL + hb + cc];
#pragma unroll
        for (int i2 = 0; i2 < 4; i2++) {
            Kt[(cc + i2) * 72 + r] = kt4[i2];
            Vt[(cc + i2) * 72 + r] = vt4[i2];
        }
    }
    __syncthreads();
    int wave = tid >> 6, lane = tid & 63, quad = lane >> 4, l16 = lane & 15;
    int wm = wave * 16;                    // d strip
    float4v acc[4];
#pragma unroll
    for (int jt = 0; jt < 4; jt++)
#pragma unroll
        for (int r = 0; r < 4; r++) acc[jt][r] = 0.0f;
#pragma unroll
    for (int ks = 0; ks < 2; ks++) {
        short8 af = *(const short8*)&Kt[(wm + l16) * 72 + ks * 32 + quad * 8];
#pragma unroll
        for (int jt = 0; jt < 4; jt++) {
            short8 bf = *(const short8*)&Vt[(jt * 16 + l16) * 72 + ks * 32 + quad * 8];
            acc[jt] = __builtin_amdgcn_mfma_f32_16x16x32_bf16(af, bf, acc[jt], 0, 0, 0);
        }
    }
    float* Sp = S + (size_t)(h * NCHUNK + c) * 4160;
#pragma unroll
    for (int jt = 0; jt < 4; jt++) {
        float4 o;
        o.x = acc[jt][0]; o.y = acc[jt][1]; o.z = acc[jt][2]; o.w = acc[jt][3];
        *(float4*)&Sp[(jt * 16 + l16) * 64 + wm + quad * 4] = o;
    }
    if (tid < 64) {
        float s = 0.f;
#pragma unroll
        for (int g = 0; g < 8; g++) {
            short8 kv8 = *(const short8*)&Kt[tid * 72 + g * 8];
#pragma unroll
            for (int i2 = 0; i2 < 8; i2++) s += b2f(((ushort_t*)&kv8)[i2]);
        }
        Sp[4096 + tid] = s;
    }
}

// ---------------- exclusive prefix over chunks: S_t -> Pb (bf16 [e][d]) + kpf (f32) ----------------
__global__ void prefix_kernel(const float* __restrict__ S, ushort_t* __restrict__ Pb,
                              float* __restrict__ kpf) {
    int h = blockIdx.x;
    int i = blockIdx.y * 256 + threadIdx.x;
    if (i >= 4160) return;
    float v[NCHUNK];
    size_t base = (size_t)h * NCHUNK * 4160 + i;
#pragma unroll
    for (int c2 = 0; c2 < NCHUNK; c2++) v[c2] = S[base + (size_t)c2 * 4160];
    float run = 0.f;
    if (i < 4096) {
        size_t pb = (size_t)h * NCHUNK * 4096 + i;
#pragma unroll
        for (int c2 = 0; c2 < NCHUNK; c2++) {
            Pb[pb + (size_t)c2 * 4096] = f2b(run);
            run += v[c2];
        }
    } else {
        size_t kb = (size_t)h * NCHUNK * 64 + (i - 4096);
#pragma unroll
        for (int c2 = 0; c2 < NCHUNK; c2++) {
            kpf[kb + (size_t)c2 * 64] = run;
            run += v[c2];
        }
    }
}

// ---------------- per-(head,chunk) output via MFMA ----------------
__global__ __launch_bounds__(256) void attn_out_mfma(const ushort_t* __restrict__ qf,
                                                     const ushort_t* __restrict__ kf,
                                                     const ushort_t* __restrict__ vb,
                                                     const ushort_t* __restrict__ Pb,
                                                     const float* __restrict__ kpf,
                                                     ushort_t* __restrict__ attn) {
    int h = blockIdx.x % NHEAD;
    int c = blockIdx.x / NHEAD;
    __shared__ ushort_t Qs[64 * 72];   // [l][d]
    __shared__ ushort_t Ks[64 * 72];   // [j][d]
    __shared__ ushort_t Pt[64 * 72];   // [e][d]
    __shared__ ushort_t Vt[64 * 72];   // [e][j]
    __shared__ float Sc[64 * 68];      // raw scores [l][j]
    __shared__ float kpl[64];
    __shared__ float denp[4][64];
    __shared__ float dnl[64];
    int tid = threadIdx.x;
    const size_t hb = (size_t)h * DHEAD;
    const size_t pcb = (size_t)(h * NCHUNK + c);
#pragma unroll
    for (int it = 0; it < 2; it++) {
        int chunk = it * 256 + tid;          // 0..511
        int r = chunk >> 3, c8 = (chunk & 7) * 8;
        int lg = c * 64 + r;
        *(uint4*)&Qs[r * 72 + c8] = *(const uint4*)&qf[(size_t)lg * DMODEL + hb + c8];
        *(uint4*)&Ks[r * 72 + c8] = *(const uint4*)&kf[(size_t)lg * DMODEL + hb + c8];
        *(uint4*)&Pt[r * 72 + c8] = *(const uint4*)&Pb[pcb * 4096 + r * 64 + c8];
    }
#pragma unroll
    for (int it = 0; it < 4; it++) {
        int r = it * 16 + (tid >> 4);
        int cc = (tid & 15) * 4;
        int lg = c * 64 + r;
        ushort_t vt4[4];
        *(uint2*)vt4 = *(const uint2*)&vb[(size_t)lg * DMODEL + hb + cc];
#pragma unroll
        for (int i2 = 0; i2 < 4; i2++) Vt[(cc + i2) * 72 + r] = vt4[i2];
    }
    if (tid < 64) kpl[tid] = kpf[pcb * 64 + tid];
    __syncthreads();
    int wave = tid >> 6, lane = tid & 63, quad = lane >> 4, l16 = lane & 15;
    int wm = wave * 16;                      // l strip
    float4v s_acc[4], n_acc[4];
#pragma unroll
    for (int jt = 0; jt < 4; jt++)
#pragma unroll
        for (int r = 0; r < 4; r++) { s_acc[jt][r] = 0.0f; n_acc[jt][r] = 0.0f; }
#pragma unroll
    for (int ks = 0; ks < 2; ks++) {
        short8 aq = *(const short8*)&Qs[(wm + l16) * 72 + ks * 32 + quad * 8];
#pragma unroll
        for (int jt = 0; jt < 4; jt++) {
            short8 bk = *(const short8*)&Ks[(jt * 16 + l16) * 72 + ks * 32 + quad * 8];
            short8 bp = *(const short8*)&Pt[(jt * 16 + l16) * 72 + ks * 32 + quad * 8];
            s_acc[jt] = __builtin_amdgcn_mfma_f32_16x16x32_bf16(aq, bk, s_acc[jt], 0, 0, 0);
            n_acc[jt] = __builtin_amdgcn_mfma_f32_16x16x32_bf16(aq, bp, n_acc[jt], 0, 0, 0);
        }
    }
#pragma unroll
    for (int jt = 0; jt < 4; jt++)
#pragma unroll
        for (int r = 0; r < 4; r++)
            Sc[(wm + quad * 4 + r) * 68 + jt * 16 + l16] = s_acc[jt][r];
    __syncthreads();
    {
        int l = tid & 63, part = tid >> 6;
        float s = 0.f;
#pragma unroll
        for (int jj = 0; jj < 16; jj++) {
            int j = part * 16 + jj;
            float v = Sc[l * 68 + j];
            s += (j <= l) ? v : 0.f;
        }
#pragma unroll
        for (int dd = 0; dd < 16; dd++) {
            int d = part * 16 + dd;
            s += b2f(Qs[l * 72 + d]) * kpl[d];
        }
        denp[part][l] = s;
    }
    __syncthreads();
    if (tid < 64) dnl[tid] = denp[0][tid] + denp[1][tid] + denp[2][tid] + denp[3][tid] + 1e-6f;
    __syncthreads();
#pragma unroll
    for (int ks = 0; ks < 2; ks++) {
        int m = wm + l16;
        float sv[8];
        *(float4*)&sv[0] = *(const float4*)&Sc[m * 68 + ks * 32 + quad * 8];
        *(float4*)&sv[4] = *(const float4*)&Sc[m * 68 + ks * 32 + quad * 8 + 4];
        ushort_t am[8];
#pragma unroll
        for (int i2 = 0; i2 < 8; i2++) {
            int j = ks * 32 + quad * 8 + i2;
            am[i2] = (j <= m) ? f2b(sv[i2]) : (ushort_t)0;
        }
        short8 af = *(short8*)am;
#pragma unroll
        for (int jt = 0; jt < 4; jt++) {
            short8 bv = *(const short8*)&Vt[(jt * 16 + l16) * 72 + ks * 32 + quad * 8];
            n_acc[jt] = __builtin_amdgcn_mfma_f32_16x16x32_bf16(af, bv, n_acc[jt], 0, 0, 0);
        }
    }
#pragma unroll
    for (int jt = 0; jt < 4; jt++) {
        int e = jt * 16 + l16;
#pragma unroll
        for (int r = 0; r < 4; r++) {
            int l = wm + quad * 4 + r;
            float o = n_acc[jt][r] / dnl[l];
            attn[(size_t)(c * 64 + l) * DMODEL + hb + e] = f2b(o);
        }
    }
}

extern "C" void kernel_launch(void* const* d_in, const int* in_sizes, int n_in,
                              void* d_out, int out_size, void* d_ws, size_t ws_size,
                              hipStream_t stream) {
    const float* x      = (const float*)d_in[0];
    const float* W_qkv  = (const float*)d_in[1];
    const float* b_qkv  = (const float*)d_in[2];
    const float* W_sem  = (const float*)d_in[3];
    const float* b_sem  = (const float*)d_in[4];
    const float* W_ctx  = (const float*)d_in[5];
    const float* b_ctx  = (const float*)d_in[6];
    const float* W_proj = (const float*)d_in[7];
    const float* b_proj = (const float*)d_in[8];
    const float* ln_g   = (const float*)d_in[9];
    const float* ln_b   = (const float*)d_in[10];
    float* out = (float*)d_out;
    float* ws  = (float*)d_ws;

    // ---- workspace layout (float-slot offsets), total 15,728,640 f = 62.9 MB ----
    // steps: 1 ln  2 transpose  3 gemm_merged(+vb)  4 gate  5 chunk_sum  6 prefix  7 attn_out  8 gemm_64
    // Region A [0, 2064384):        Wt_merged(2-3) -> S[0,1597440)(5-6) -> attnb[0,786432)(7-8)
    // Region B [2064384, 2359296):  Wt_proj(2-8) — never overlaid
    // Region C [2359296, 3145728):  xb(1-3) -> qf(4-7)
    // Region D [3145728, 3932160):  xnb(1-3) -> kf(4-7)
    // Region E [3932160, 14942208): qsc(3-4) -> Pb[3932160,4718592)+kpf[4718592,4743168)(6-7)
    // Region F [14942208, 15728640): vb(3-7)
    ushort_t* Wt_merged = (ushort_t*)(ws);
    ushort_t* Wt_proj   = (ushort_t*)(ws + 2064384);
    ushort_t* xb        = (ushort_t*)(ws + 2359296);
    ushort_t* xnb       = (ushort_t*)(ws + 3145728);
    float*    qsc       = ws + 3932160;
    ushort_t* vb        = (ushort_t*)(ws + 14942208);
    ushort_t* qf        = (ushort_t*)(ws + 2359296);
    ushort_t* kf        = (ushort_t*)(ws + 3145728);
    float*    S         = ws;
    ushort_t* Pb        = (ushort_t*)(ws + 3932160);
    float*    kpf       = ws + 4718592;
    ushort_t* attnb     = (ushort_t*)(ws);

    ln_kernel<<<LSEQ, 256, 0, stream>>>(x, ln_g, ln_b, xnb, xb);
    transpose_all_kernel<<<dim3(72, 24, 4), 256, 0, stream>>>(W_qkv, W_sem, W_ctx, Wt_merged,
                                                              W_proj, Wt_proj);

    gemm_merged_kernel<<<dim3(NMERGED / 128, LSEQ / 128), 256, 0, stream>>>(
        xnb, xb, Wt_merged, b_qkv, b_sem, b_ctx, qsc, vb);

    gate_feat_kernel<<<(LSEQ * DMODEL / 4) / 256, 256, 0, stream>>>(qsc, qf, kf);
    chunk_sum_mfma<<<NHEAD * NCHUNK, 256, 0, stream>>>(kf, vb, S);
    prefix_kernel<<<dim3(NHEAD, 17), 256, 0, stream>>>(S, Pb, kpf);
    attn_out_mfma<<<NHEAD * NCHUNK, 256, 0, stream>>>(qf, kf, vb, Pb, kpf, attnb);

    gemm_64_kernel<<<dim3(768 / 64, LSEQ / 64), 256, 0, stream>>>(attnb, Wt_proj, b_proj, out, 768, 768);
}